// Round 1
// baseline (630.150 us; speedup 1.0000x reference)
//
#include <hip/hip_runtime.h>
#include <math.h>

#define SEQ 2048
#define DIM 1024
#define HD  128
#define NB  8
#define M_TOT (NB * SEQ)   // 16384

// ---------------------------------------------------------------------------
// Kernel 1: fused QKV projection.  out[M,128] = x[M,1024] @ W[1024,128] + b
// grid = (M/64, 3); block = 256.  BM=64, BN=128, BK=16, per-thread 4x8.
// ---------------------------------------------------------------------------
__global__ __launch_bounds__(256) void qkv_gemm(
    const float* __restrict__ x,
    const float* __restrict__ Wq, const float* __restrict__ bq,
    const float* __restrict__ Wk, const float* __restrict__ bk,
    const float* __restrict__ Wv, const float* __restrict__ bv,
    float* __restrict__ Qo, float* __restrict__ Ko, float* __restrict__ Vo)
{
    const int mt  = blockIdx.x;
    const int mat = blockIdx.y;           // 0=Q 1=K 2=V
    const float* __restrict__ W    = (mat == 0) ? Wq : (mat == 1) ? Wk : Wv;
    const float* __restrict__ bias = (mat == 0) ? bq : (mat == 1) ? bk : bv;
    float* __restrict__ out        = (mat == 0) ? Qo : (mat == 1) ? Ko : Vo;

    const int row0 = mt * 64;
    const int t = threadIdx.x;

    __shared__ float As[16][65];    // [kk][row]  (x tile, k-major)
    __shared__ float Bs[16][132];   // [kk][col]  (W tile)

    const int lr = t >> 2, lc = t & 3;     // x loader: row lr, float4 #lc
    const int wr = t >> 4, wc = t & 15;    // W loader: row wr, float4 #wc (+16)
    const int ty = t >> 4, tx = t & 15;    // compute: rows ty*4, cols tx*8

    float acc[4][8];
    #pragma unroll
    for (int i = 0; i < 4; ++i)
        #pragma unroll
        for (int j = 0; j < 8; ++j) acc[i][j] = 0.0f;

    for (int k0 = 0; k0 < DIM; k0 += 16) {
        float4 xa = *(const float4*)(x + (size_t)(row0 + lr) * DIM + (k0 + lc * 4));
        float4 wa = *(const float4*)(W + (size_t)(k0 + wr) * HD + wc * 4);
        float4 wb = *(const float4*)(W + (size_t)(k0 + wr) * HD + (wc + 16) * 4);
        As[lc * 4 + 0][lr] = xa.x;
        As[lc * 4 + 1][lr] = xa.y;
        As[lc * 4 + 2][lr] = xa.z;
        As[lc * 4 + 3][lr] = xa.w;
        *(float4*)&Bs[wr][wc * 4]        = wa;
        *(float4*)&Bs[wr][(wc + 16) * 4] = wb;
        __syncthreads();
        #pragma unroll
        for (int kk = 0; kk < 16; ++kk) {
            float a0 = As[kk][ty * 4 + 0];
            float a1 = As[kk][ty * 4 + 1];
            float a2 = As[kk][ty * 4 + 2];
            float a3 = As[kk][ty * 4 + 3];
            float4 b0 = *(const float4*)&Bs[kk][tx * 8];
            float4 b1 = *(const float4*)&Bs[kk][tx * 8 + 4];
            float bb[8] = {b0.x, b0.y, b0.z, b0.w, b1.x, b1.y, b1.z, b1.w};
            #pragma unroll
            for (int j = 0; j < 8; ++j) {
                acc[0][j] += a0 * bb[j];
                acc[1][j] += a1 * bb[j];
                acc[2][j] += a2 * bb[j];
                acc[3][j] += a3 * bb[j];
            }
        }
        __syncthreads();
    }

    float4 bv0 = *(const float4*)(bias + tx * 8);
    float4 bv1 = *(const float4*)(bias + tx * 8 + 4);
    #pragma unroll
    for (int i = 0; i < 4; ++i) {
        float4 o0, o1;
        o0.x = acc[i][0] + bv0.x; o0.y = acc[i][1] + bv0.y;
        o0.z = acc[i][2] + bv0.z; o0.w = acc[i][3] + bv0.w;
        o1.x = acc[i][4] + bv1.x; o1.y = acc[i][5] + bv1.y;
        o1.z = acc[i][6] + bv1.z; o1.w = acc[i][7] + bv1.w;
        float* orow = out + (size_t)(row0 + ty * 4 + i) * HD + tx * 8;
        *(float4*)(orow)     = o0;
        *(float4*)(orow + 4) = o1;
    }
}

// ---------------------------------------------------------------------------
// Kernel 2: causal flash attention, fp32.  TQ=TK=32, 256 threads.
// thread t: query row r = t>>3 (0..31), dim-group g = t&7 (dims d = g+8*i).
// Per-row softmax state (m,l) replicated across the 8 lanes of a row group
// (row groups never cross waves: lane = (r&7)*8 + g).
// grid = 512 (1-D); L -> batch = L&7, rank = L>>3, qt = balance remap(rank).
// ---------------------------------------------------------------------------
__global__ __launch_bounds__(256) void flash_attn(
    const float* __restrict__ Q, const float* __restrict__ K,
    const float* __restrict__ V, float* __restrict__ out)
{
    const int L    = blockIdx.x;
    const int b    = L & 7;
    const int rank = L >> 3;                 // 0..63
    // pair heavy (late) tiles with light (early) tiles across CUs
    const int qt = (rank < 32) ? (rank * 2) : (63 - (rank - 32) * 2);
    const int q0 = qt * 32;

    __shared__ float Qs[32][132];
    __shared__ float Ks[32][132];
    __shared__ float Vs[32][132];
    __shared__ float Ps[32][33];

    const int t = threadIdx.x;
    const int r = t >> 3;
    const int g = t & 7;

    // load Q tile, pre-scaled by sqrt(D) = 32
    {
        const float* qrow = Q + (size_t)(b * SEQ + q0 + r) * HD + g * 16;
        #pragma unroll
        for (int u = 0; u < 4; ++u) {
            float4 v = *(const float4*)(qrow + u * 4);
            float* dst = &Qs[r][g * 16 + u * 4];
            dst[0] = v.x * 32.0f; dst[1] = v.y * 32.0f;
            dst[2] = v.z * 32.0f; dst[3] = v.w * 32.0f;
        }
    }

    float m_r = -INFINITY;
    float l_r = 0.0f;
    float accv[16];
    #pragma unroll
    for (int i = 0; i < 16; ++i) accv[i] = 0.0f;

    for (int j0 = 0; j0 <= q0; j0 += 32) {
        __syncthreads();   // Ks/Vs (and Qs on iter 0) safe to (over)write
        {
            const float* krow = K + (size_t)(b * SEQ + j0 + r) * HD + g * 16;
            const float* vrow = V + (size_t)(b * SEQ + j0 + r) * HD + g * 16;
            #pragma unroll
            for (int u = 0; u < 4; ++u) {
                *(float4*)&Ks[r][g * 16 + u * 4] = *(const float4*)(krow + u * 4);
                *(float4*)&Vs[r][g * 16 + u * 4] = *(const float4*)(vrow + u * 4);
            }
        }
        __syncthreads();

        // scores: thread handles keys jj = g, g+8, g+16, g+24
        float s0 = 0.0f, s1 = 0.0f, s2 = 0.0f, s3 = 0.0f;
        #pragma unroll 8
        for (int d = 0; d < HD; d += 4) {
            float4 qv = *(const float4*)&Qs[r][d];
            float4 k0 = *(const float4*)&Ks[g][d];
            float4 k1 = *(const float4*)&Ks[g + 8][d];
            float4 k2 = *(const float4*)&Ks[g + 16][d];
            float4 k3 = *(const float4*)&Ks[g + 24][d];
            s0 += qv.x * k0.x + qv.y * k0.y + qv.z * k0.z + qv.w * k0.w;
            s1 += qv.x * k1.x + qv.y * k1.y + qv.z * k1.z + qv.w * k1.w;
            s2 += qv.x * k2.x + qv.y * k2.y + qv.z * k2.z + qv.w * k2.w;
            s3 += qv.x * k3.x + qv.y * k3.y + qv.z * k3.z + qv.w * k3.w;
        }
        if (j0 == q0) {   // partial (diagonal) tile: mask key jj > r
            if (g      > r) s0 = -INFINITY;
            if (g + 8  > r) s1 = -INFINITY;
            if (g + 16 > r) s2 = -INFINITY;
            if (g + 24 > r) s3 = -INFINITY;
        }

        // online softmax (row state replicated across the 8 g-lanes)
        float lm = fmaxf(fmaxf(s0, s1), fmaxf(s2, s3));
        #pragma unroll
        for (int o = 1; o < 8; o <<= 1) lm = fmaxf(lm, __shfl_xor(lm, o, 64));
        const float mnew = fmaxf(m_r, lm);
        const float p0 = __expf(s0 - mnew);
        const float p1 = __expf(s1 - mnew);
        const float p2 = __expf(s2 - mnew);
        const float p3 = __expf(s3 - mnew);
        float ls = p0 + p1 + p2 + p3;
        #pragma unroll
        for (int o = 1; o < 8; o <<= 1) ls += __shfl_xor(ls, o, 64);
        const float alpha = __expf(m_r - mnew);
        l_r = l_r * alpha + ls;
        m_r = mnew;
        #pragma unroll
        for (int i = 0; i < 16; ++i) accv[i] *= alpha;

        Ps[r][g]      = p0;
        Ps[r][g + 8]  = p1;
        Ps[r][g + 16] = p2;
        Ps[r][g + 24] = p3;
        // Ps row is written & read by the same wave (DS ops are in-order per
        // wave) — no barrier needed before the PV accumulation.
        #pragma unroll 4
        for (int jj = 0; jj < 32; ++jj) {
            float p = Ps[r][jj];
            #pragma unroll
            for (int i = 0; i < 16; ++i) accv[i] += p * Vs[jj][g + 8 * i];
        }
    }

    const float inv = 1.0f / l_r;
    float* orow = out + (size_t)(b * SEQ + q0 + r) * HD;
    #pragma unroll
    for (int i = 0; i < 16; ++i) orow[g + 8 * i] = accv[i] * inv;
}

// ---------------------------------------------------------------------------
extern "C" void kernel_launch(void* const* d_in, const int* in_sizes, int n_in,
                              void* d_out, int out_size, void* d_ws, size_t ws_size,
                              hipStream_t stream) {
    const float* x  = (const float*)d_in[0];
    const float* Wq = (const float*)d_in[1];
    const float* bq = (const float*)d_in[2];
    const float* Wk = (const float*)d_in[3];
    const float* bk = (const float*)d_in[4];
    const float* Wv = (const float*)d_in[5];
    const float* bv = (const float*)d_in[6];
    float* out = (float*)d_out;

    float* Q = (float*)d_ws;                       // 16384*128 floats = 8 MB
    float* K = Q + (size_t)M_TOT * HD;
    float* V = K + (size_t)M_TOT * HD;

    dim3 g1(M_TOT / 64, 3);
    qkv_gemm<<<g1, 256, 0, stream>>>(x, Wq, bq, Wk, bk, Wv, bv, Q, K, V);

    flash_attn<<<512, 256, 0, stream>>>(Q, K, V, out);
}

// Round 2
// 310.941 us; speedup vs baseline: 2.0266x; 2.0266x over previous
//
#include <hip/hip_runtime.h>
#include <math.h>

#define SEQ 2048
#define DIM 1024
#define HD  128
#define NB  8
#define M_TOT (NB * SEQ)   // 16384

typedef __attribute__((ext_vector_type(8))) short   short8;   // 8 x bf16 (4 VGPRs)
typedef __attribute__((ext_vector_type(4))) float   floatx4;  // MFMA acc

// bf16 round-to-nearest-even helpers
__device__ __forceinline__ unsigned short f2bf(float f) {
    unsigned u = __builtin_bit_cast(unsigned, f);
    u += 0x7FFFu + ((u >> 16) & 1u);
    return (unsigned short)(u >> 16);
}
__device__ __forceinline__ float bf2f(unsigned short h) {
    unsigned u = ((unsigned)h) << 16;
    return __builtin_bit_cast(float, u);
}

// async global->LDS, 16 B per lane (dest = uniform base + lane*16)
__device__ __forceinline__ void async16(const void* g, void* l) {
    __builtin_amdgcn_global_load_lds(
        (const __attribute__((address_space(1))) unsigned int*)g,
        (__attribute__((address_space(3))) unsigned int*)l, 16, 0, 0);
}

#define MFMA16(a, b, c) __builtin_amdgcn_mfma_f32_16x16x32_bf16((a), (b), (c), 0, 0, 0)

// ---------------------------------------------------------------------------
// Kernel 0: W -> Wt (transposed, bf16 hi/lo split).  Wt[mat][n=128][k=1024]
// ---------------------------------------------------------------------------
__global__ __launch_bounds__(256) void wt_prep(
    const float* __restrict__ Wq, const float* __restrict__ Wk, const float* __restrict__ Wv,
    unsigned short* __restrict__ Wth, unsigned short* __restrict__ Wtl)
{
    int idx = blockIdx.x * 256 + threadIdx.x;       // [mat][n][k] flat, 3*128*1024
    int k   = idx & 1023;
    int n   = (idx >> 10) & 127;
    int mat = idx >> 17;
    const float* W = (mat == 0) ? Wq : (mat == 1) ? Wk : Wv;
    float v = W[k * HD + n];
    unsigned short hi = f2bf(v);
    Wth[idx] = hi;
    Wtl[idx] = f2bf(v - bf2f(hi));
}

// ---------------------------------------------------------------------------
// Kernel 1: fused QKV projection, MFMA bf16x3.
// grid=256 blocks x 256 thr.  BM=64, BN=384 (3 mats x 128), BK=32.
// LDS frag-major: A frags (mt 0..3, p 0..1) = idx mt*2+p; B frags at 8 + ntg*2+p.
// wave w: m-half = w&1 (frags 2mh,2mh+1), nt-group = w>>1 (ntg g*12..g*12+11).
// Epilogue: Q -> *32, split -> Qh/Ql;  K -> split -> Kh/Kl;  V -> bf16 -> Vt[b][d][s].
// ---------------------------------------------------------------------------
__global__ __launch_bounds__(256) void qkv_gemm(
    const float* __restrict__ x,
    const unsigned short* __restrict__ Wth, const unsigned short* __restrict__ Wtl,
    const float* __restrict__ bq, const float* __restrict__ bk, const float* __restrict__ bv,
    unsigned short* __restrict__ Qh, unsigned short* __restrict__ Ql,
    unsigned short* __restrict__ Kh, unsigned short* __restrict__ Kl,
    unsigned short* __restrict__ Vt)
{
    __shared__ short lds[56 * 512];                 // 56 frags x 1 KB = 56 KB

    const int t    = threadIdx.x;
    const int lane = t & 63;
    const int w    = t >> 6;          // wave 0..3
    const int lrow = lane & 15;
    const int quad = lane >> 4;
    const int R0   = blockIdx.x * 64;

    const int mh = w & 1;             // rows mh*32 .. mh*32+31
    const int ng = w >> 1;            // ntg = ng*12 .. ng*12+11

    floatx4 acc[2][12];
    const floatx4 zf = {0.f, 0.f, 0.f, 0.f};
    #pragma unroll
    for (int i = 0; i < 2; ++i)
        #pragma unroll
        for (int j = 0; j < 12; ++j) acc[i][j] = zf;

    for (int k0 = 0; k0 < DIM; k0 += 32) {
        __syncthreads();
        // --- stage x tile: wave w stages A frag mt=w (its 16 rows) ---
        {
            const float* xp = x + (size_t)(R0 + w * 16 + lrow) * DIM + k0 + quad * 8;
            float4 xa = *(const float4*)xp;
            float4 xb = *(const float4*)(xp + 4);
            float xv[8] = {xa.x, xa.y, xa.z, xa.w, xb.x, xb.y, xb.z, xb.w};
            short8 hv, lv;
            #pragma unroll
            for (int i = 0; i < 8; ++i) {
                unsigned short h = f2bf(xv[i]);
                hv[i] = (short)h;
                lv[i] = (short)f2bf(xv[i] - bf2f(h));
            }
            *(short8*)&lds[(w * 2 + 0) * 512 + lane * 8] = hv;
            *(short8*)&lds[(w * 2 + 1) * 512 + lane * 8] = lv;
        }
        // --- stage Wt frags: wave w stages B frag ids w*12 .. w*12+11 ---
        #pragma unroll
        for (int i = 0; i < 12; ++i) {
            int id  = w * 12 + i;
            int ntg = id >> 1, p = id & 1;
            const unsigned short* src = (p ? Wtl : Wth)
                + (size_t)(ntg * 16 + lrow) * 1024 + k0 + quad * 8;
            async16(src, &lds[(8 + id) * 512 + lane * 8]);
        }
        __syncthreads();
        // --- compute ---
        short8 a[2][2];
        #pragma unroll
        for (int mi = 0; mi < 2; ++mi)
            #pragma unroll
            for (int p = 0; p < 2; ++p)
                a[mi][p] = *(short8*)&lds[((2 * mh + mi) * 2 + p) * 512 + lane * 8];
        #pragma unroll
        for (int i = 0; i < 12; ++i) {
            int ntg = ng * 12 + i;
            short8 bh = *(short8*)&lds[(8 + ntg * 2 + 0) * 512 + lane * 8];
            short8 bl = *(short8*)&lds[(8 + ntg * 2 + 1) * 512 + lane * 8];
            #pragma unroll
            for (int mi = 0; mi < 2; ++mi) {
                acc[mi][i] = MFMA16(a[mi][0], bh, acc[mi][i]);
                acc[mi][i] = MFMA16(a[mi][0], bl, acc[mi][i]);
                acc[mi][i] = MFMA16(a[mi][1], bh, acc[mi][i]);
            }
        }
    }

    // --- epilogue ---
    #pragma unroll
    for (int i = 0; i < 12; ++i) {
        int ntg = ng * 12 + i;
        int mat = ntg >> 3;
        int col = (ntg & 7) * 16 + lrow;
        const float* bias = (mat == 0) ? bq : (mat == 1) ? bk : bv;
        float bval = bias[col];
        #pragma unroll
        for (int mi = 0; mi < 2; ++mi) {
            #pragma unroll
            for (int reg = 0; reg < 4; ++reg) {
                int gm = R0 + (2 * mh + mi) * 16 + quad * 4 + reg;   // global row
                float v = acc[mi][i][reg] + bval;
                if (mat == 0) {
                    v *= 32.0f;                                      // sqrt(D) fold
                    unsigned short h = f2bf(v);
                    Qh[(size_t)gm * HD + col] = h;
                    Ql[(size_t)gm * HD + col] = f2bf(v - bf2f(h));
                } else if (mat == 1) {
                    unsigned short h = f2bf(v);
                    Kh[(size_t)gm * HD + col] = h;
                    Kl[(size_t)gm * HD + col] = f2bf(v - bf2f(h));
                } else {
                    int b = gm >> 11, s = gm & 2047;
                    Vt[((size_t)b * HD + col) * SEQ + s] = f2bf(v);
                }
            }
        }
    }
}

// ---------------------------------------------------------------------------
// Kernel 2: causal flash attention, MFMA bf16x3 (QK) + bf16 (PV).
// grid=256: block -> batch = blk&7 (XCD-local K/V), j = blk>>3 (0..31).
// Block processes 32-row strips {63-j (waves 0,1), j (waves 2,3)} concurrently,
// sharing one 64-key staging tile per iteration. Perfect static balance.
// LDS frags: K (nt*8+kc*2+p, 32) | V (32+nt*2+kc, 16) | P (48+w*2+kc, 8).
// ---------------------------------------------------------------------------
__global__ __launch_bounds__(256) void flash_attn(
    const unsigned short* __restrict__ Qh, const unsigned short* __restrict__ Ql,
    const unsigned short* __restrict__ Kh, const unsigned short* __restrict__ Kl,
    const unsigned short* __restrict__ Vt, float* __restrict__ out)
{
    __shared__ short lds[56 * 512];                 // 56 KB

    const int t    = threadIdx.x;
    const int lane = t & 63;
    const int w    = t >> 6;
    const int lrow = lane & 15;
    const int quad = lane >> 4;

    const int b  = blockIdx.x & 7;
    const int j  = blockIdx.x >> 3;                 // 0..31
    const int sA = 63 - j;                          // heavy strip (32 rows)
    const int sB = j;                               // light strip
    const int myStrip = (w < 2) ? sA : sB;
    const int R = myStrip * 32 + (w & 1) * 16;      // my 16 rows (batch-local)
    const int ntiles = (sA * 32 + 95) >> 6;         // 64-key tiles

    const size_t kbase = (size_t)b * SEQ * HD;
    const size_t vbase = (size_t)b * HD * SEQ;

    // Q fragments (pre-scaled by 32, hi/lo), register-resident
    short8 qf[4][2];
    #pragma unroll
    for (int kc = 0; kc < 4; ++kc) {
        size_t off = kbase + (size_t)(R + lrow) * HD + kc * 32 + quad * 8;
        qf[kc][0] = *(const short8*)(Qh + off);
        qf[kc][1] = *(const short8*)(Ql + off);
    }

    const floatx4 zf = {0.f, 0.f, 0.f, 0.f};
    floatx4 accO[8];
    #pragma unroll
    for (int i = 0; i < 8; ++i) accO[i] = zf;
    float m_[4] = {-INFINITY, -INFINITY, -INFINITY, -INFINITY};
    float l_[4] = {0.f, 0.f, 0.f, 0.f};

    for (int it = 0; it < ntiles; ++it) {
        const int j0 = it * 64;
        __syncthreads();                            // prior tile's reads done
        // --- stage K hi/lo + Vt: wave w stages frag ids w*12 .. w*12+11 ---
        #pragma unroll
        for (int i = 0; i < 12; ++i) {
            int id = w * 12 + i;
            const unsigned short* src;
            if (id < 32) {                          // K frag (nt,kc,p)
                int nt = id >> 3, kc = (id >> 1) & 3, p = id & 1;
                src = (p ? Kl : Kh) + kbase
                    + (size_t)(j0 + nt * 16 + lrow) * HD + kc * 32 + quad * 8;
            } else {                                // V frag (nt,kc)
                int v = id - 32, nt = v >> 1, kc = v & 1;
                src = Vt + vbase + (size_t)(nt * 16 + lrow) * SEQ
                    + j0 + kc * 32 + quad * 8;
            }
            async16(src, &lds[id * 512 + lane * 8]);
        }
        __syncthreads();                            // staging visible (vmcnt drained)

        if (j0 > R) continue;                       // tile entirely above my rows

        // --- QK^T (bf16x3) ---
        floatx4 S[4] = {zf, zf, zf, zf};
        #pragma unroll
        for (int nt = 0; nt < 4; ++nt) {
            #pragma unroll
            for (int kc = 0; kc < 4; ++kc) {
                short8 kh = *(short8*)&lds[(nt * 8 + kc * 2 + 0) * 512 + lane * 8];
                short8 kl = *(short8*)&lds[(nt * 8 + kc * 2 + 1) * 512 + lane * 8];
                S[nt] = MFMA16(qf[kc][0], kh, S[nt]);
                S[nt] = MFMA16(qf[kc][0], kl, S[nt]);
                S[nt] = MFMA16(qf[kc][1], kh, S[nt]);
            }
        }
        // --- causal mask on diagonal tiles ---
        if (j0 + 63 > R) {
            #pragma unroll
            for (int nt = 0; nt < 4; ++nt) {
                int key = j0 + nt * 16 + lrow;
                #pragma unroll
                for (int reg = 0; reg < 4; ++reg) {
                    int row = R + quad * 4 + reg;
                    if (key > row) S[nt][reg] = -INFINITY;
                }
            }
        }
        // --- online softmax (row = quad*4+reg, cols across 16-lane group) ---
        float alpha[4];
        #pragma unroll
        for (int reg = 0; reg < 4; ++reg) {
            float mx = fmaxf(fmaxf(S[0][reg], S[1][reg]), fmaxf(S[2][reg], S[3][reg]));
            #pragma unroll
            for (int h = 1; h < 16; h <<= 1) mx = fmaxf(mx, __shfl_xor(mx, h));
            float mnew = fmaxf(m_[reg], mx);
            alpha[reg] = __expf(m_[reg] - mnew);
            m_[reg] = mnew;
            float p0 = __expf(S[0][reg] - mnew);
            float p1 = __expf(S[1][reg] - mnew);
            float p2 = __expf(S[2][reg] - mnew);
            float p3 = __expf(S[3][reg] - mnew);
            S[0][reg] = p0; S[1][reg] = p1; S[2][reg] = p2; S[3][reg] = p3;
            float ls = p0 + p1 + p2 + p3;
            #pragma unroll
            for (int h = 1; h < 16; h <<= 1) ls += __shfl_xor(ls, h);
            l_[reg] = l_[reg] * alpha[reg] + ls;
        }
        #pragma unroll
        for (int i = 0; i < 8; ++i) {
            #pragma unroll
            for (int reg = 0; reg < 4; ++reg) accO[i][reg] *= alpha[reg];
        }
        // --- P: C-layout regs -> A-layout LDS frags (same-wave, no barrier) ---
        #pragma unroll
        for (int nt = 0; nt < 4; ++nt) {
            #pragma unroll
            for (int reg = 0; reg < 4; ++reg) {
                int key = nt * 16 + lrow;           // 0..63
                int kc = key >> 5, jj = key & 7, q2 = (key >> 3) & 3;
                int lane2 = (quad * 4 + reg) + (q2 << 4);
                lds[(48 + w * 2 + kc) * 512 + lane2 * 8 + jj] = (short)f2bf(S[nt][reg]);
            }
        }
        short8 pf0 = *(short8*)&lds[(48 + w * 2 + 0) * 512 + lane * 8];
        short8 pf1 = *(short8*)&lds[(48 + w * 2 + 1) * 512 + lane * 8];
        // --- PV ---
        #pragma unroll
        for (int nt = 0; nt < 8; ++nt) {
            short8 v0 = *(short8*)&lds[(32 + nt * 2 + 0) * 512 + lane * 8];
            short8 v1 = *(short8*)&lds[(32 + nt * 2 + 1) * 512 + lane * 8];
            accO[nt] = MFMA16(pf0, v0, accO[nt]);
            accO[nt] = MFMA16(pf1, v1, accO[nt]);
        }
    }

    // --- epilogue ---
    float inv[4];
    #pragma unroll
    for (int reg = 0; reg < 4; ++reg) inv[reg] = 1.0f / l_[reg];
    #pragma unroll
    for (int nt = 0; nt < 8; ++nt) {
        #pragma unroll
        for (int reg = 0; reg < 4; ++reg) {
            size_t o = ((size_t)(b * SEQ + R + quad * 4 + reg)) * HD + nt * 16 + lrow;
            out[o] = accO[nt][reg] * inv[reg];
        }
    }
}

// ---------------------------------------------------------------------------
extern "C" void kernel_launch(void* const* d_in, const int* in_sizes, int n_in,
                              void* d_out, int out_size, void* d_ws, size_t ws_size,
                              hipStream_t stream) {
    const float* x  = (const float*)d_in[0];
    const float* Wq = (const float*)d_in[1];
    const float* bq = (const float*)d_in[2];
    const float* Wk = (const float*)d_in[3];
    const float* bk = (const float*)d_in[4];
    const float* Wv = (const float*)d_in[5];
    const float* bv = (const float*)d_in[6];
    float* out = (float*)d_out;

    // workspace layout (bytes): 5 x 4 MB bf16 activations + 2 x 0.75 MB Wt
    unsigned short* Qh  = (unsigned short*)d_ws;                 // 16384x128
    unsigned short* Ql  = Qh  + (size_t)M_TOT * HD;
    unsigned short* Kh  = Ql  + (size_t)M_TOT * HD;
    unsigned short* Kl  = Kh  + (size_t)M_TOT * HD;
    unsigned short* Vt  = Kl  + (size_t)M_TOT * HD;              // [8][128][2048]
    unsigned short* Wth = Vt  + (size_t)M_TOT * HD;              // [3][128][1024]
    unsigned short* Wtl = Wth + (size_t)3 * HD * DIM;

    wt_prep<<<(3 * HD * DIM) / 256, 256, 0, stream>>>(Wq, Wk, Wv, Wth, Wtl);
    qkv_gemm<<<256, 256, 0, stream>>>(x, Wth, Wtl, bq, bk, bv, Qh, Ql, Kh, Kl, Vt);
    flash_attn<<<256, 256, 0, stream>>>(Qh, Ql, Kh, Kl, Vt, out);
}

// Round 3
// 274.432 us; speedup vs baseline: 2.2962x; 1.1330x over previous
//
#include <hip/hip_runtime.h>
#include <math.h>

#define SEQ 2048
#define DIM 1024
#define HD  128
#define NB  8
#define M_TOT (NB * SEQ)   // 16384

typedef __attribute__((ext_vector_type(8))) short   short8;   // 8 x bf16 (4 VGPRs)
typedef __attribute__((ext_vector_type(4))) float   floatx4;  // MFMA acc

__device__ __forceinline__ unsigned short f2bf(float f) {
    unsigned u = __builtin_bit_cast(unsigned, f);
    u += 0x7FFFu + ((u >> 16) & 1u);
    return (unsigned short)(u >> 16);
}
__device__ __forceinline__ float bf2f(unsigned short h) {
    unsigned u = ((unsigned)h) << 16;
    return __builtin_bit_cast(float, u);
}
__device__ __forceinline__ void async16(const void* g, void* l) {
    __builtin_amdgcn_global_load_lds(
        (const __attribute__((address_space(1))) unsigned int*)g,
        (__attribute__((address_space(3))) unsigned int*)l, 16, 0, 0);
}

#define MFMA16(a, b, c) __builtin_amdgcn_mfma_f32_16x16x32_bf16((a), (b), (c), 0, 0, 0)

// ---------------------------------------------------------------------------
// Kernel 0: W -> Wt (transposed, bf16 hi/lo split).  Wt[mat][n=128][k=1024]
// ---------------------------------------------------------------------------
__global__ __launch_bounds__(256) void wt_prep(
    const float* __restrict__ Wq, const float* __restrict__ Wk, const float* __restrict__ Wv,
    unsigned short* __restrict__ Wth, unsigned short* __restrict__ Wtl)
{
    int idx = blockIdx.x * 256 + threadIdx.x;       // [mat][n][k] flat
    int k   = idx & 1023;
    int n   = (idx >> 10) & 127;
    int mat = idx >> 17;
    const float* W = (mat == 0) ? Wq : (mat == 1) ? Wk : Wv;
    float v = W[k * HD + n];
    unsigned short hi = f2bf(v);
    Wth[idx] = hi;
    Wtl[idx] = f2bf(v - bf2f(hi));
}

// ---------------------------------------------------------------------------
// Kernel 1: QKV projection.  grid = (3 mats, 256 mtiles), 256 thr, 4 waves.
// BM=64, BN=128 (one mat), BK=64.  Wave w: mh=w&1 (m-frags 2mh..2mh+1),
// nh=w>>1 (n-frags 4nh..4nh+3).  Q,K: bf16x3; V: hi*hi only.
// LDS frag-major 1KB frags: A id=(mf*2+kc)*2+p (0..15), B id=16+(nf*2+kc)*2+p.
// ---------------------------------------------------------------------------
__global__ __launch_bounds__(256) void qkv_gemm(
    const float* __restrict__ x,
    const unsigned short* __restrict__ Wth, const unsigned short* __restrict__ Wtl,
    const float* __restrict__ bq, const float* __restrict__ bk, const float* __restrict__ bv,
    unsigned short* __restrict__ Qh, unsigned short* __restrict__ Ql,
    unsigned short* __restrict__ Kh, unsigned short* __restrict__ Kl,
    unsigned short* __restrict__ Vt)
{
    __shared__ short lds[48 * 512];                 // 48 KB

    const int t    = threadIdx.x;
    const int lane = t & 63;
    const int w    = t >> 6;
    const int lrow = lane & 15;
    const int quad = lane >> 4;

    const int mat = blockIdx.x;                     // 0=Q 1=K 2=V
    const int R0  = blockIdx.y * 64;
    const int mh  = w & 1;
    const int nh  = w >> 1;

    floatx4 acc[2][4];
    const floatx4 zf = {0.f, 0.f, 0.f, 0.f};
    #pragma unroll
    for (int i = 0; i < 2; ++i)
        #pragma unroll
        for (int j = 0; j < 4; ++j) acc[i][j] = zf;

    for (int k0 = 0; k0 < DIM; k0 += 64) {
        __syncthreads();
        // stage A: wave w -> m-frag mf=w (16 rows), both kc, hi/lo split
        #pragma unroll
        for (int kc = 0; kc < 2; ++kc) {
            const float* xp = x + (size_t)(R0 + w * 16 + lrow) * DIM + k0 + kc * 32 + quad * 8;
            float4 xa = *(const float4*)xp;
            float4 xb = *(const float4*)(xp + 4);
            float xv[8] = {xa.x, xa.y, xa.z, xa.w, xb.x, xb.y, xb.z, xb.w};
            short8 hv, lv;
            #pragma unroll
            for (int i = 0; i < 8; ++i) {
                unsigned short h = f2bf(xv[i]);
                hv[i] = (short)h;
                lv[i] = (short)f2bf(xv[i] - bf2f(h));
            }
            *(short8*)&lds[((w * 2 + kc) * 2 + 0) * 512 + lane * 8] = hv;
            *(short8*)&lds[((w * 2 + kc) * 2 + 1) * 512 + lane * 8] = lv;
        }
        // stage B: wave w stages 8 of 32 frags (async)
        #pragma unroll
        for (int i = 0; i < 8; ++i) {
            int id = w * 8 + i;                     // (nf*2+kc)*2+p
            int p = id & 1, kc = (id >> 1) & 1, nf = id >> 2;
            const unsigned short* src = (p ? Wtl : Wth) + (size_t)mat * (HD * DIM)
                + (size_t)(nf * 16 + lrow) * DIM + k0 + kc * 32 + quad * 8;
            async16(src, &lds[(16 + id) * 512 + lane * 8]);
        }
        __syncthreads();

        short8 a[2][2][2];                          // [mi][kc][p]
        #pragma unroll
        for (int mi = 0; mi < 2; ++mi)
            #pragma unroll
            for (int kc = 0; kc < 2; ++kc)
                #pragma unroll
                for (int p = 0; p < 2; ++p)
                    a[mi][kc][p] = *(short8*)&lds[(((2 * mh + mi) * 2 + kc) * 2 + p) * 512 + lane * 8];

        #pragma unroll
        for (int ni = 0; ni < 4; ++ni) {
            int nf = nh * 4 + ni;
            #pragma unroll
            for (int kc = 0; kc < 2; ++kc) {
                short8 bh = *(short8*)&lds[(16 + (nf * 2 + kc) * 2 + 0) * 512 + lane * 8];
                #pragma unroll
                for (int mi = 0; mi < 2; ++mi)
                    acc[mi][ni] = MFMA16(a[mi][kc][0], bh, acc[mi][ni]);
                if (mat < 2) {                      // uniform branch
                    short8 bl = *(short8*)&lds[(16 + (nf * 2 + kc) * 2 + 1) * 512 + lane * 8];
                    #pragma unroll
                    for (int mi = 0; mi < 2; ++mi) {
                        acc[mi][ni] = MFMA16(a[mi][kc][0], bl, acc[mi][ni]);
                        acc[mi][ni] = MFMA16(a[mi][kc][1], bh, acc[mi][ni]);
                    }
                }
            }
        }
    }

    // epilogue
    const float* bias = (mat == 0) ? bq : (mat == 1) ? bk : bv;
    #pragma unroll
    for (int ni = 0; ni < 4; ++ni) {
        int col = (nh * 4 + ni) * 16 + lrow;
        float bval = bias[col];
        #pragma unroll
        for (int mi = 0; mi < 2; ++mi) {
            #pragma unroll
            for (int reg = 0; reg < 4; ++reg) {
                int gm = R0 + (2 * mh + mi) * 16 + quad * 4 + reg;
                float v = acc[mi][ni][reg] + bval;
                if (mat == 0) {
                    v *= 32.0f;                     // fold sqrt(D)
                    unsigned short h = f2bf(v);
                    Qh[(size_t)gm * HD + col] = h;
                    Ql[(size_t)gm * HD + col] = f2bf(v - bf2f(h));
                } else if (mat == 1) {
                    unsigned short h = f2bf(v);
                    Kh[(size_t)gm * HD + col] = h;
                    Kl[(size_t)gm * HD + col] = f2bf(v - bf2f(h));
                } else {
                    int b = gm >> 11, s = gm & 2047;
                    Vt[((size_t)b * HD + col) * SEQ + s] = f2bf(v);
                }
            }
        }
    }
}

// ---------------------------------------------------------------------------
// Kernel 2: causal flash attention.  grid = 512: rank -> b=rank&7 (XCD-local
// K/V), strip s = 63-(rank>>3) (heavy-first dispatch).  Block = 32 Q rows.
// 4 waves = 2 row-halves (mh) x 2 key-halves (kh); each (mh,kh) keeps an
// independent online softmax over its 32-key half of every 64-key tile and
// the two key-halves merge once at the end (no per-tile cross-wave traffic).
// LDS frags: K id=nt*8+kc*2+p (0..31) | V id=32+df*2+kc (32..47) | P 48+w.
// ---------------------------------------------------------------------------
__global__ __launch_bounds__(256) void flash_attn(
    const unsigned short* __restrict__ Qh, const unsigned short* __restrict__ Ql,
    const unsigned short* __restrict__ Kh, const unsigned short* __restrict__ Kl,
    const unsigned short* __restrict__ Vt, float* __restrict__ out)
{
    __shared__ short lds[52 * 512];                 // 52 KB

    const int t    = threadIdx.x;
    const int lane = t & 63;
    const int w    = t >> 6;
    const int lrow = lane & 15;
    const int quad = lane >> 4;

    const int rank = blockIdx.x;
    const int b    = rank & 7;
    const int s    = 63 - (rank >> 3);              // heavy strips first
    const int mh   = w & 1;
    const int kh   = w >> 1;
    const int R    = s * 32 + mh * 16;              // wave's first row (batch-local)
    const int T    = (s * 32 + 95) >> 6;            // 64-key tiles

    const size_t kbase = (size_t)b * SEQ * HD;
    const size_t vbase = (size_t)b * HD * SEQ;

    short8 qf[4][2];
    #pragma unroll
    for (int kc = 0; kc < 4; ++kc) {
        size_t off = kbase + (size_t)(R + lrow) * HD + kc * 32 + quad * 8;
        qf[kc][0] = *(const short8*)(Qh + off);
        qf[kc][1] = *(const short8*)(Ql + off);
    }

    const floatx4 zf = {0.f, 0.f, 0.f, 0.f};
    floatx4 accO[8];
    #pragma unroll
    for (int i = 0; i < 8; ++i) accO[i] = zf;
    float m_[4] = {-INFINITY, -INFINITY, -INFINITY, -INFINITY};
    float l_[4] = {0.f, 0.f, 0.f, 0.f};

    for (int it = 0; it < T; ++it) {
        const int j0 = it * 64;
        __syncthreads();
        #pragma unroll
        for (int i = 0; i < 12; ++i) {
            int id = w * 12 + i;
            const unsigned short* src;
            if (id < 32) {                          // K frag: nt,kc,p
                int nt = id >> 3, kc = (id >> 1) & 3, p = id & 1;
                src = (p ? Kl : Kh) + kbase
                    + (size_t)(j0 + nt * 16 + lrow) * HD + kc * 32 + quad * 8;
            } else {                                // V frag: df,kc
                int v = id - 32, df = v >> 1, kc = v & 1;
                src = Vt + vbase + (size_t)(df * 16 + lrow) * SEQ
                    + j0 + kc * 32 + quad * 8;
            }
            async16(src, &lds[id * 512 + lane * 8]);
        }
        __syncthreads();

        // QK^T over my 32-key half (bf16x3)
        floatx4 S[2] = {zf, zf};
        #pragma unroll
        for (int ntl = 0; ntl < 2; ++ntl) {
            int nt = kh * 2 + ntl;
            #pragma unroll
            for (int kc = 0; kc < 4; ++kc) {
                short8 khf = *(short8*)&lds[(nt * 8 + kc * 2 + 0) * 512 + lane * 8];
                short8 klf = *(short8*)&lds[(nt * 8 + kc * 2 + 1) * 512 + lane * 8];
                S[ntl] = MFMA16(qf[kc][0], khf, S[ntl]);
                S[ntl] = MFMA16(qf[kc][0], klf, S[ntl]);
                S[ntl] = MFMA16(qf[kc][1], khf, S[ntl]);
            }
        }
        // causal mask
        if (j0 + kh * 32 + 31 > R) {
            #pragma unroll
            for (int ntl = 0; ntl < 2; ++ntl) {
                int key = j0 + (kh * 2 + ntl) * 16 + lrow;
                #pragma unroll
                for (int reg = 0; reg < 4; ++reg) {
                    if (key > R + quad * 4 + reg) S[ntl][reg] = -INFINITY;
                }
            }
        }
        // online softmax (independent per key-half); clamp handles all-masked
        float alpha[4];
        #pragma unroll
        for (int reg = 0; reg < 4; ++reg) {
            float mx = fmaxf(S[0][reg], S[1][reg]);
            #pragma unroll
            for (int h = 1; h < 16; h <<= 1) mx = fmaxf(mx, __shfl_xor(mx, h));
            float mnew = fmaxf(fmaxf(m_[reg], mx), -1e30f);
            alpha[reg] = __expf(m_[reg] - mnew);
            m_[reg] = mnew;
            float p0 = __expf(S[0][reg] - mnew);
            float p1 = __expf(S[1][reg] - mnew);
            S[0][reg] = p0; S[1][reg] = p1;
            float ls = p0 + p1;
            #pragma unroll
            for (int h = 1; h < 16; h <<= 1) ls += __shfl_xor(ls, h);
            l_[reg] = l_[reg] * alpha[reg] + ls;
        }
        #pragma unroll
        for (int i = 0; i < 8; ++i)
            #pragma unroll
            for (int reg = 0; reg < 4; ++reg) accO[i][reg] *= alpha[reg];

        // P: C-layout -> A-layout LDS (same-wave round trip, no barrier)
        #pragma unroll
        for (int ntl = 0; ntl < 2; ++ntl) {
            #pragma unroll
            for (int reg = 0; reg < 4; ++reg) {
                int kloc = ntl * 16 + lrow;          // 0..31
                int jj = kloc & 7, q2 = (kloc >> 3) & 3;
                int lane2 = (quad * 4 + reg) + (q2 << 4);
                lds[(48 + w) * 512 + lane2 * 8 + jj] = (short)f2bf(S[ntl][reg]);
            }
        }
        short8 pf = *(short8*)&lds[(48 + w) * 512 + lane * 8];
        #pragma unroll
        for (int df = 0; df < 8; ++df) {
            short8 vf = *(short8*)&lds[(32 + df * 2 + kh) * 512 + lane * 8];
            accO[df] = MFMA16(pf, vf, accO[df]);
        }
    }

    // merge the two key-halves (once per block)
    __syncthreads();
    float* fl   = (float*)lds;
    float* Obuf = fl;                               // [mh][16][128]
    float* mlb  = fl + 4096;                        // [kh][mh][row][2]
    if (lrow == 0) {
        #pragma unroll
        for (int reg = 0; reg < 4; ++reg) {
            int row = quad * 4 + reg;
            mlb[((kh * 2 + mh) * 16 + row) * 2 + 0] = m_[reg];
            mlb[((kh * 2 + mh) * 16 + row) * 2 + 1] = l_[reg];
        }
    }
    __syncthreads();
    float myw[4];
    #pragma unroll
    for (int reg = 0; reg < 4; ++reg) {
        int row = quad * 4 + reg;
        float mo  = mlb[(((1 - kh) * 2 + mh) * 16 + row) * 2 + 0];
        float lo_ = mlb[(((1 - kh) * 2 + mh) * 16 + row) * 2 + 1];
        float M = fmaxf(m_[reg], mo);
        float d = l_[reg] * __expf(m_[reg] - M) + lo_ * __expf(mo - M);
        myw[reg] = __expf(m_[reg] - M) / d;
    }
    if (kh == 0) {
        #pragma unroll
        for (int df = 0; df < 8; ++df)
            #pragma unroll
            for (int reg = 0; reg < 4; ++reg)
                Obuf[(mh * 16 + quad * 4 + reg) * 128 + df * 16 + lrow] =
                    accO[df][reg] * myw[reg];
    }
    __syncthreads();
    if (kh == 1) {
        #pragma unroll
        for (int df = 0; df < 8; ++df) {
            #pragma unroll
            for (int reg = 0; reg < 4; ++reg) {
                float v = Obuf[(mh * 16 + quad * 4 + reg) * 128 + df * 16 + lrow]
                        + accO[df][reg] * myw[reg];
                size_t o = ((size_t)(b * SEQ + R + quad * 4 + reg)) * HD + df * 16 + lrow;
                out[o] = v;
            }
        }
    }
}

// ---------------------------------------------------------------------------
extern "C" void kernel_launch(void* const* d_in, const int* in_sizes, int n_in,
                              void* d_out, int out_size, void* d_ws, size_t ws_size,
                              hipStream_t stream) {
    const float* x  = (const float*)d_in[0];
    const float* Wq = (const float*)d_in[1];
    const float* bq = (const float*)d_in[2];
    const float* Wk = (const float*)d_in[3];
    const float* bk = (const float*)d_in[4];
    const float* Wv = (const float*)d_in[5];
    const float* bv = (const float*)d_in[6];
    float* out = (float*)d_out;

    unsigned short* Qh  = (unsigned short*)d_ws;
    unsigned short* Ql  = Qh  + (size_t)M_TOT * HD;
    unsigned short* Kh  = Ql  + (size_t)M_TOT * HD;
    unsigned short* Kl  = Kh  + (size_t)M_TOT * HD;
    unsigned short* Vt  = Kl  + (size_t)M_TOT * HD;
    unsigned short* Wth = Vt  + (size_t)M_TOT * HD;
    unsigned short* Wtl = Wth + (size_t)3 * HD * DIM;

    wt_prep<<<(3 * HD * DIM) / 256, 256, 0, stream>>>(Wq, Wk, Wv, Wth, Wtl);
    qkv_gemm<<<dim3(3, 256), 256, 0, stream>>>(x, Wth, Wtl, bq, bk, bv, Qh, Ql, Kh, Kl, Vt);
    flash_attn<<<512, 256, 0, stream>>>(Qh, Ql, Kh, Kl, Vt, out);
}

// Round 4
// 240.783 us; speedup vs baseline: 2.6171x; 1.1398x over previous
//
#include <hip/hip_runtime.h>
#include <math.h>

#define SEQ 2048
#define DIM 1024
#define HD  128
#define NB  8
#define M_TOT (NB * SEQ)   // 16384

typedef __attribute__((ext_vector_type(8))) short   short8;   // 8 x bf16 (4 VGPRs)
typedef __attribute__((ext_vector_type(4))) float   floatx4;  // MFMA acc

__device__ __forceinline__ unsigned short f2bf(float f) {
    unsigned u = __builtin_bit_cast(unsigned, f);
    u += 0x7FFFu + ((u >> 16) & 1u);
    return (unsigned short)(u >> 16);
}
__device__ __forceinline__ float bf2f(unsigned short h) {
    unsigned u = ((unsigned)h) << 16;
    return __builtin_bit_cast(float, u);
}
__device__ __forceinline__ void async16(const void* g, void* l) {
    __builtin_amdgcn_global_load_lds(
        (const __attribute__((address_space(1))) unsigned int*)g,
        (__attribute__((address_space(3))) unsigned int*)l, 16, 0, 0);
}

#define MFMA16(a, b, c) __builtin_amdgcn_mfma_f32_16x16x32_bf16((a), (b), (c), 0, 0, 0)

// ---------------------------------------------------------------------------
// Kernel 0: W -> Wt (transposed, bf16 hi/lo split).  Wt[mat][n=128][k=1024]
// ---------------------------------------------------------------------------
__global__ __launch_bounds__(256) void wt_prep(
    const float* __restrict__ Wq, const float* __restrict__ Wk, const float* __restrict__ Wv,
    unsigned short* __restrict__ Wth, unsigned short* __restrict__ Wtl)
{
    int idx = blockIdx.x * 256 + threadIdx.x;       // [mat][n][k] flat
    int k   = idx & 1023;
    int n   = (idx >> 10) & 127;
    int mat = idx >> 17;
    const float* W = (mat == 0) ? Wq : (mat == 1) ? Wk : Wv;
    float v = W[k * HD + n];
    unsigned short hi = f2bf(v);
    Wth[idx] = hi;
    Wtl[idx] = f2bf(v - bf2f(hi));
}

// ---------------------------------------------------------------------------
// Kernel 1: QKV projection.  grid = (3 mats, 256 mtiles), 256 thr, 4 waves.
// BM=64, BN=128, BK=32, LDS double-buffered (2 x 24 frags = 48 KB, 3 blk/CU).
// One barrier per k-iter: stage tile t+1 (async W + reg-split x) overlaps
// compute of tile t.  Q,K: bf16x3; V: hi*hi only.
// Frag ids (per buf q): A = q*24 + mf*2+p (mf 0..3); B = q*24+8 + nf*2+p.
// ---------------------------------------------------------------------------
__global__ __launch_bounds__(256) void qkv_gemm(
    const float* __restrict__ x,
    const unsigned short* __restrict__ Wth, const unsigned short* __restrict__ Wtl,
    const float* __restrict__ bq, const float* __restrict__ bk, const float* __restrict__ bv,
    unsigned short* __restrict__ Qh, unsigned short* __restrict__ Ql,
    unsigned short* __restrict__ Kh, unsigned short* __restrict__ Kl,
    unsigned short* __restrict__ Vt)
{
    __shared__ short lds[48 * 512];                 // 48 KB

    const int t    = threadIdx.x;
    const int lane = t & 63;
    const int w    = t >> 6;
    const int lrow = lane & 15;
    const int quad = lane >> 4;

    const int mat = blockIdx.x;                     // 0=Q 1=K 2=V
    const int R0  = blockIdx.y * 64;
    const int mh  = w & 1;
    const int nh  = w >> 1;

    floatx4 acc[2][4];
    const floatx4 zf = {0.f, 0.f, 0.f, 0.f};
    #pragma unroll
    for (int i = 0; i < 2; ++i)
        #pragma unroll
        for (int j = 0; j < 4; ++j) acc[i][j] = zf;

    const size_t wmat = (size_t)mat * (HD * DIM);

    // ---- staging helper (wave w: A frag mf=w, B frags w*4..w*4+3) ----
    auto stage = [&](int k0, int q) {
        const float* xp = x + (size_t)(R0 + w * 16 + lrow) * DIM + k0 + quad * 8;
        float4 xa = *(const float4*)xp;
        float4 xb = *(const float4*)(xp + 4);
        float xv[8] = {xa.x, xa.y, xa.z, xa.w, xb.x, xb.y, xb.z, xb.w};
        short8 hv, lv;
        #pragma unroll
        for (int i = 0; i < 8; ++i) {
            unsigned short h = f2bf(xv[i]);
            hv[i] = (short)h;
            lv[i] = (short)f2bf(xv[i] - bf2f(h));
        }
        *(short8*)&lds[(q * 24 + w * 2 + 0) * 512 + lane * 8] = hv;
        *(short8*)&lds[(q * 24 + w * 2 + 1) * 512 + lane * 8] = lv;
        #pragma unroll
        for (int i = 0; i < 4; ++i) {
            int id = w * 4 + i;                     // nf*2+p
            int p = id & 1, nf = id >> 1;
            const unsigned short* src = (p ? Wtl : Wth) + wmat
                + (size_t)(nf * 16 + lrow) * DIM + k0 + quad * 8;
            async16(src, &lds[(q * 24 + 8 + id) * 512 + lane * 8]);
        }
    };

    stage(0, 0);
    for (int it = 0; it < 32; ++it) {
        __syncthreads();                            // buf[it&1] staged; prev reads done
        if (it < 31) stage((it + 1) * 32, (it + 1) & 1);
        const int q = it & 1;

        short8 a[2][2];
        #pragma unroll
        for (int mi = 0; mi < 2; ++mi)
            #pragma unroll
            for (int p = 0; p < 2; ++p)
                a[mi][p] = *(short8*)&lds[(q * 24 + (2 * mh + mi) * 2 + p) * 512 + lane * 8];

        #pragma unroll
        for (int ni = 0; ni < 4; ++ni) {
            int nf = nh * 4 + ni;
            short8 bh = *(short8*)&lds[(q * 24 + 8 + nf * 2 + 0) * 512 + lane * 8];
            #pragma unroll
            for (int mi = 0; mi < 2; ++mi)
                acc[mi][ni] = MFMA16(a[mi][0], bh, acc[mi][ni]);
            if (mat < 2) {                          // uniform branch
                short8 bl = *(short8*)&lds[(q * 24 + 8 + nf * 2 + 1) * 512 + lane * 8];
                #pragma unroll
                for (int mi = 0; mi < 2; ++mi) {
                    acc[mi][ni] = MFMA16(a[mi][0], bl, acc[mi][ni]);
                    acc[mi][ni] = MFMA16(a[mi][1], bh, acc[mi][ni]);
                }
            }
        }
    }

    // epilogue
    const float* bias = (mat == 0) ? bq : (mat == 1) ? bk : bv;
    #pragma unroll
    for (int ni = 0; ni < 4; ++ni) {
        int col = (nh * 4 + ni) * 16 + lrow;
        float bval = bias[col];
        #pragma unroll
        for (int mi = 0; mi < 2; ++mi) {
            #pragma unroll
            for (int reg = 0; reg < 4; ++reg) {
                int gm = R0 + (2 * mh + mi) * 16 + quad * 4 + reg;
                float v = acc[mi][ni][reg] + bval;
                if (mat == 0) {
                    v *= 32.0f;                     // fold sqrt(D)
                    unsigned short h = f2bf(v);
                    Qh[(size_t)gm * HD + col] = h;
                    Ql[(size_t)gm * HD + col] = f2bf(v - bf2f(h));
                } else if (mat == 1) {
                    unsigned short h = f2bf(v);
                    Kh[(size_t)gm * HD + col] = h;
                    Kl[(size_t)gm * HD + col] = f2bf(v - bf2f(h));
                } else {
                    int b = gm >> 11, s = gm & 2047;
                    Vt[((size_t)b * HD + col) * SEQ + s] = f2bf(v);
                }
            }
        }
    }
}

// ---------------------------------------------------------------------------
// Kernel 2: causal flash attention, optionally split-K over key tiles.
// split=1: grid 1024, idx -> b=idx&7, h=(idx>>3)&1, s=63-(idx>>4);
//          block h covers tile range [h?Th:0, h?T:Th), writes unnormalized
//          partial O + (M,L) per row.  split=0: grid 512, full range, final.
// Within a block: 4 waves = 2 row-halves (mh) x 2 key-halves (kh) with
// independent online softmax per kh, merged via LDS at the end.
// LDS frags: K id=nt*8+kc*2+p (0..31) | V id=32+df*2+kc | P 48+w.
// ---------------------------------------------------------------------------
__global__ __launch_bounds__(256) void flash_attn(
    const unsigned short* __restrict__ Qh, const unsigned short* __restrict__ Ql,
    const unsigned short* __restrict__ Kh, const unsigned short* __restrict__ Kl,
    const unsigned short* __restrict__ Vt, float* __restrict__ out,
    float* __restrict__ Opart, float* __restrict__ ML, int split)
{
    __shared__ short lds[52 * 512];                 // 52 KB

    const int t    = threadIdx.x;
    const int lane = t & 63;
    const int w    = t >> 6;
    const int lrow = lane & 15;
    const int quad = lane >> 4;

    const int idx = blockIdx.x;
    const int b   = idx & 7;
    const int h   = split ? ((idx >> 3) & 1) : 0;
    const int s   = split ? (63 - (idx >> 4)) : (63 - (idx >> 3));
    const int T   = (s + 2) >> 1;                   // 64-key tiles in strip
    const int Th  = (T + 1) >> 1;
    const int t0  = split ? (h ? Th : 0) : 0;
    const int t1  = split ? (h ? T : Th) : T;

    if (split && t0 >= t1) {                        // empty half (s==0,h==1)
        float* op = Opart + (size_t)idx * 4096;
        for (int i = t; i < 4096; i += 256) op[i] = 0.0f;
        if (t < 32) { ML[(idx * 32 + t) * 2] = -1e30f; ML[(idx * 32 + t) * 2 + 1] = 0.0f; }
        return;
    }

    const int mh = w & 1;
    const int kh = w >> 1;
    const int R  = s * 32 + mh * 16;                // wave's first row (batch-local)

    const size_t kbase = (size_t)b * SEQ * HD;
    const size_t vbase = (size_t)b * HD * SEQ;

    short8 qf[4][2];
    #pragma unroll
    for (int kc = 0; kc < 4; ++kc) {
        size_t off = kbase + (size_t)(R + lrow) * HD + kc * 32 + quad * 8;
        qf[kc][0] = *(const short8*)(Qh + off);
        qf[kc][1] = *(const short8*)(Ql + off);
    }

    const floatx4 zf = {0.f, 0.f, 0.f, 0.f};
    floatx4 accO[8];
    #pragma unroll
    for (int i = 0; i < 8; ++i) accO[i] = zf;
    float m_[4] = {-1e30f, -1e30f, -1e30f, -1e30f};
    float l_[4] = {0.f, 0.f, 0.f, 0.f};

    for (int it = t0; it < t1; ++it) {
        const int j0 = it * 64;
        __syncthreads();
        #pragma unroll
        for (int i = 0; i < 12; ++i) {
            int id = w * 12 + i;
            const unsigned short* src;
            if (id < 32) {                          // K frag: nt,kc,p
                int nt = id >> 3, kc = (id >> 1) & 3, p = id & 1;
                src = (p ? Kl : Kh) + kbase
                    + (size_t)(j0 + nt * 16 + lrow) * HD + kc * 32 + quad * 8;
            } else {                                // V frag: df,kc
                int v = id - 32, df = v >> 1, kc = v & 1;
                src = Vt + vbase + (size_t)(df * 16 + lrow) * SEQ
                    + j0 + kc * 32 + quad * 8;
            }
            async16(src, &lds[id * 512 + lane * 8]);
        }
        __syncthreads();

        // QK^T over my 32-key half (bf16x3)
        floatx4 S[2] = {zf, zf};
        #pragma unroll
        for (int ntl = 0; ntl < 2; ++ntl) {
            int nt = kh * 2 + ntl;
            #pragma unroll
            for (int kc = 0; kc < 4; ++kc) {
                short8 khf = *(short8*)&lds[(nt * 8 + kc * 2 + 0) * 512 + lane * 8];
                short8 klf = *(short8*)&lds[(nt * 8 + kc * 2 + 1) * 512 + lane * 8];
                S[ntl] = MFMA16(qf[kc][0], khf, S[ntl]);
                S[ntl] = MFMA16(qf[kc][0], klf, S[ntl]);
                S[ntl] = MFMA16(qf[kc][1], khf, S[ntl]);
            }
        }
        // causal mask (only the strip's last tile triggers this)
        if (j0 + kh * 32 + 31 > R) {
            #pragma unroll
            for (int ntl = 0; ntl < 2; ++ntl) {
                int key = j0 + (kh * 2 + ntl) * 16 + lrow;
                #pragma unroll
                for (int reg = 0; reg < 4; ++reg) {
                    if (key > R + quad * 4 + reg) S[ntl][reg] = -INFINITY;
                }
            }
        }
        // online softmax (independent per key-half)
        float alpha[4];
        #pragma unroll
        for (int reg = 0; reg < 4; ++reg) {
            float mx = fmaxf(S[0][reg], S[1][reg]);
            #pragma unroll
            for (int hh = 1; hh < 16; hh <<= 1) mx = fmaxf(mx, __shfl_xor(mx, hh));
            float mnew = fmaxf(fmaxf(m_[reg], mx), -1e30f);
            alpha[reg] = __expf(m_[reg] - mnew);
            m_[reg] = mnew;
            float p0 = __expf(S[0][reg] - mnew);
            float p1 = __expf(S[1][reg] - mnew);
            S[0][reg] = p0; S[1][reg] = p1;
            float ls = p0 + p1;
            #pragma unroll
            for (int hh = 1; hh < 16; hh <<= 1) ls += __shfl_xor(ls, hh);
            l_[reg] = l_[reg] * alpha[reg] + ls;
        }
        #pragma unroll
        for (int i = 0; i < 8; ++i)
            #pragma unroll
            for (int reg = 0; reg < 4; ++reg) accO[i][reg] *= alpha[reg];

        // P: C-layout -> A-layout LDS (same-wave round trip, no barrier)
        #pragma unroll
        for (int ntl = 0; ntl < 2; ++ntl) {
            #pragma unroll
            for (int reg = 0; reg < 4; ++reg) {
                int kloc = ntl * 16 + lrow;          // 0..31
                int jj = kloc & 7, q2 = (kloc >> 3) & 3;
                int lane2 = (quad * 4 + reg) + (q2 << 4);
                lds[(48 + w) * 512 + lane2 * 8 + jj] = (short)f2bf(S[ntl][reg]);
            }
        }
        short8 pf = *(short8*)&lds[(48 + w) * 512 + lane * 8];
        #pragma unroll
        for (int df = 0; df < 8; ++df) {
            short8 vf = *(short8*)&lds[(32 + df * 2 + kh) * 512 + lane * 8];
            accO[df] = MFMA16(pf, vf, accO[df]);
        }
    }

    // ---- merge the two key-halves (once per block) ----
    __syncthreads();
    float* fl   = (float*)lds;
    float* Obuf = fl;                               // [32][128]
    float* mlb  = fl + 4096;                        // [kh][mh][row][2]
    if (lrow == 0) {
        #pragma unroll
        for (int reg = 0; reg < 4; ++reg) {
            int row = quad * 4 + reg;
            mlb[((kh * 2 + mh) * 16 + row) * 2 + 0] = m_[reg];
            mlb[((kh * 2 + mh) * 16 + row) * 2 + 1] = l_[reg];
        }
    }
    __syncthreads();
    float myw[4], Mrow[4], Drow[4];
    #pragma unroll
    for (int reg = 0; reg < 4; ++reg) {
        int row = quad * 4 + reg;
        float mo  = mlb[(((1 - kh) * 2 + mh) * 16 + row) * 2 + 0];
        float lo_ = mlb[(((1 - kh) * 2 + mh) * 16 + row) * 2 + 1];
        float M = fmaxf(m_[reg], mo);
        float d = l_[reg] * __expf(m_[reg] - M) + lo_ * __expf(mo - M);
        Mrow[reg] = M; Drow[reg] = d;
        myw[reg] = split ? __expf(m_[reg] - M) : (__expf(m_[reg] - M) / d);
    }
    if (kh == 0) {
        #pragma unroll
        for (int df = 0; df < 8; ++df)
            #pragma unroll
            for (int reg = 0; reg < 4; ++reg)
                Obuf[(mh * 16 + quad * 4 + reg) * 128 + df * 16 + lrow] =
                    accO[df][reg] * myw[reg];
    }
    __syncthreads();
    if (kh == 1) {
        if (split) {
            float* op = Opart + (size_t)idx * 4096;
            #pragma unroll
            for (int df = 0; df < 8; ++df) {
                #pragma unroll
                for (int reg = 0; reg < 4; ++reg) {
                    int row = mh * 16 + quad * 4 + reg;
                    op[row * 128 + df * 16 + lrow] =
                        Obuf[row * 128 + df * 16 + lrow] + accO[df][reg] * myw[reg];
                }
            }
            if (lrow == 0) {
                #pragma unroll
                for (int reg = 0; reg < 4; ++reg) {
                    int row = mh * 16 + quad * 4 + reg;
                    ML[(idx * 32 + row) * 2 + 0] = Mrow[reg];
                    ML[(idx * 32 + row) * 2 + 1] = Drow[reg];
                }
            }
        } else {
            #pragma unroll
            for (int df = 0; df < 8; ++df) {
                #pragma unroll
                for (int reg = 0; reg < 4; ++reg) {
                    float v = Obuf[(mh * 16 + quad * 4 + reg) * 128 + df * 16 + lrow]
                            + accO[df][reg] * myw[reg];
                    size_t o = ((size_t)(b * SEQ + R + quad * 4 + reg)) * HD + df * 16 + lrow;
                    out[o] = v;
                }
            }
        }
    }
}

// ---------------------------------------------------------------------------
// Kernel 3: split-K merge.  One float4 per thread; 524288 threads.
// ---------------------------------------------------------------------------
__global__ __launch_bounds__(256) void splitk_merge(
    const float* __restrict__ Opart, const float* __restrict__ ML,
    float* __restrict__ out)
{
    int tid = blockIdx.x * 256 + threadIdx.x;
    int row = tid >> 5, c4 = tid & 31;
    int b = row >> 11, r = row & 2047, s = r >> 5, rr = r & 31;
    int i0 = ((63 - s) << 4) + b;                   // h=0 block
    int i1 = i0 + 8;                                // h=1 block
    float m0 = ML[(i0 * 32 + rr) * 2], l0 = ML[(i0 * 32 + rr) * 2 + 1];
    float m1 = ML[(i1 * 32 + rr) * 2], l1 = ML[(i1 * 32 + rr) * 2 + 1];
    float M  = fmaxf(m0, m1);
    float w0 = __expf(m0 - M), w1 = __expf(m1 - M);
    float inv = 1.0f / (w0 * l0 + w1 * l1);
    float4 a  = *(const float4*)&Opart[((size_t)i0 * 32 + rr) * 128 + c4 * 4];
    float4 bb = *(const float4*)&Opart[((size_t)i1 * 32 + rr) * 128 + c4 * 4];
    float4 o;
    o.x = (w0 * a.x + w1 * bb.x) * inv;
    o.y = (w0 * a.y + w1 * bb.y) * inv;
    o.z = (w0 * a.z + w1 * bb.z) * inv;
    o.w = (w0 * a.w + w1 * bb.w) * inv;
    *(float4*)&out[(size_t)row * 128 + c4 * 4] = o;
}

// ---------------------------------------------------------------------------
extern "C" void kernel_launch(void* const* d_in, const int* in_sizes, int n_in,
                              void* d_out, int out_size, void* d_ws, size_t ws_size,
                              hipStream_t stream) {
    const float* x  = (const float*)d_in[0];
    const float* Wq = (const float*)d_in[1];
    const float* bq = (const float*)d_in[2];
    const float* Wk = (const float*)d_in[3];
    const float* bk = (const float*)d_in[4];
    const float* Wv = (const float*)d_in[5];
    const float* bv = (const float*)d_in[6];
    float* out = (float*)d_out;

    unsigned short* Qh  = (unsigned short*)d_ws;
    unsigned short* Ql  = Qh  + (size_t)M_TOT * HD;
    unsigned short* Kh  = Ql  + (size_t)M_TOT * HD;
    unsigned short* Kl  = Kh  + (size_t)M_TOT * HD;
    unsigned short* Vt  = Kl  + (size_t)M_TOT * HD;
    unsigned short* Wth = Vt  + (size_t)M_TOT * HD;
    unsigned short* Wtl = Wth + (size_t)3 * HD * DIM;
    float* Opart = (float*)(Wtl + (size_t)3 * HD * DIM);   // 1024 x 32 x 128 f32
    float* ML    = Opart + (size_t)1024 * 32 * 128;        // 1024 x 32 x 2 f32

    const size_t need = 22544384ULL + 16777216ULL + 262144ULL;   // 39.6 MB
    const int split = (ws_size >= need) ? 1 : 0;

    wt_prep<<<(3 * HD * DIM) / 256, 256, 0, stream>>>(Wq, Wk, Wv, Wth, Wtl);
    qkv_gemm<<<dim3(3, 256), 256, 0, stream>>>(x, Wth, Wtl, bq, bk, bv, Qh, Ql, Kh, Kl, Vt);
    flash_attn<<<split ? 1024 : 512, 256, 0, stream>>>(Qh, Ql, Kh, Kl, Vt, out, Opart, ML, split);
    if (split) splitk_merge<<<2048, 256, 0, stream>>>(Opart, ML, out);
}